// Round 1
// baseline (4264.981 us; speedup 1.0000x reference)
//
#include <hip/hip_runtime.h>
#include <hip/hip_bf16.h>
#include <cstdint>

// LSTM: B=256, T=512, F=256, H=512.
// Strategy (round 0, correctness + sane perf):
//  - prep kernel: convert concat([W;U]) (gate order i,f,o,c) to bf16,
//    TRANSPOSED layout BT[col][k] (col in [0,2048), k in [0,768)) so MFMA
//    B-fragments are contiguous 16B loads.
//  - 512 step kernels (graph-captured): per block, A=[x_t | h_{t-1}] tile
//    [32 rows x 768] staged to LDS as bf16; GEMM vs 64 gate cols via
//    mfma_f32_16x16x32_bf16; fused sigmoid/tanh gate math; c state in ws;
//    h_t written straight into d_out[:, t, :] (h_{t-1} read from d_out).
//  - t==0 branch treats h/c as zero -> no state init needed, deterministic.
// ws usage: BT 2048*768*2B = 3 MB at offset 0; C 256*512*4B = 512 KB after.

#define B_   256
#define T_   512
#define F_   256
#define H_   512
#define K_   768     // F_ + H_
#define NG_  2048    // 4*H_

typedef __attribute__((ext_vector_type(8))) short short8;
typedef __attribute__((ext_vector_type(4))) float f32x4;

static __device__ __forceinline__ unsigned short f2bf(float f) {
  union { float f; unsigned u; } v; v.f = f;
  unsigned r = v.u + 0x7FFFu + ((v.u >> 16) & 1u);   // round-to-nearest-even
  return (unsigned short)(r >> 16);
}

__global__ void prep_weights(const float* __restrict__ Wi, const float* __restrict__ Wf,
                             const float* __restrict__ Wo, const float* __restrict__ Wc,
                             const float* __restrict__ Ui, const float* __restrict__ Uf,
                             const float* __restrict__ Uo, const float* __restrict__ Uc,
                             unsigned short* __restrict__ BT) {
  int idx = blockIdx.x * 256 + threadIdx.x;
  if (idx >= NG_ * K_) return;
  int col = idx / K_;
  int k   = idx - col * K_;
  int gate = col >> 9;       // 0:i 1:f 2:o 3:c  (reference concat order)
  int hc   = col & 511;
  const float* Wg = (gate == 0) ? Wi : (gate == 1) ? Wf : (gate == 2) ? Wo : Wc;
  const float* Ug = (gate == 0) ? Ui : (gate == 1) ? Uf : (gate == 2) ? Uo : Uc;
  float v = (k < F_) ? Wg[k * H_ + hc] : Ug[(k - F_) * H_ + hc];
  BT[idx] = f2bf(v);
}

// grid: 256 blocks = 8 row-groups (32 batch rows) x 32 col-groups (16 h-cols
// -> 64 gate cols, one 16-col strip per gate). block: 256 threads = 4 waves,
// wave w computes gate w's [32 x 16] preactivation tile.
__global__ __launch_bounds__(256)
void lstm_step(const float* __restrict__ x,
               const unsigned short* __restrict__ BT,
               const float* __restrict__ bi, const float* __restrict__ bf_,
               const float* __restrict__ bo, const float* __restrict__ bc,
               float* __restrict__ C,
               float* __restrict__ out,
               int t) {
  __shared__ unsigned short Ash[32][K_ + 8];   // +8 bf16 pad: 2-way-max banks
  __shared__ float Gsh[4][32][16];

  const int tid = threadIdx.x;
  const int rg = blockIdx.x & 7;    // row group
  const int cg = blockIdx.x >> 3;   // col group

  // ---- stage A = [x_t | h_{t-1}] as bf16 into LDS ----
  #pragma unroll
  for (int j = 0; j < 8; ++j) {                 // x part: 32 x 256
    int f = tid + 256 * j;                      // 0..2047 float4s
    int row = f >> 6, k4 = f & 63;
    const float4 v = *reinterpret_cast<const float4*>(
        x + ((size_t)((rg * 32 + row) * T_ + t)) * F_ + k4 * 4);
    ushort4 s; s.x = f2bf(v.x); s.y = f2bf(v.y); s.z = f2bf(v.z); s.w = f2bf(v.w);
    *reinterpret_cast<ushort4*>(&Ash[row][k4 * 4]) = s;
  }
  if (t > 0) {
    #pragma unroll
    for (int j = 0; j < 16; ++j) {              // h part: 32 x 512
      int f = tid + 256 * j;                    // 0..4095 float4s
      int row = f >> 7, k4 = f & 127;
      const float4 v = *reinterpret_cast<const float4*>(
          out + ((size_t)((rg * 32 + row)) * T_ + (t - 1)) * H_ + k4 * 4);
      ushort4 s; s.x = f2bf(v.x); s.y = f2bf(v.y); s.z = f2bf(v.z); s.w = f2bf(v.w);
      *reinterpret_cast<ushort4*>(&Ash[row][F_ + k4 * 4]) = s;
    }
  } else {
    #pragma unroll
    for (int j = 0; j < 16; ++j) {
      int f = tid + 256 * j;
      int row = f >> 7, k4 = f & 127;
      ushort4 s; s.x = 0; s.y = 0; s.z = 0; s.w = 0;
      *reinterpret_cast<ushort4*>(&Ash[row][F_ + k4 * 4]) = s;
    }
  }
  __syncthreads();

  // ---- MFMA: [32 x 768] @ [768 x 16] per wave (wave = gate) ----
  const int wave = tid >> 6, lane = tid & 63;
  const int l15 = lane & 15, l4 = lane >> 4;
  const unsigned short* Bp =
      BT + (size_t)((wave << 9) + (cg << 4) + l15) * K_;   // col-major strip
  f32x4 acc0 = {0.f, 0.f, 0.f, 0.f};
  f32x4 acc1 = {0.f, 0.f, 0.f, 0.f};
  #pragma unroll
  for (int kk = 0; kk < 24; ++kk) {
    int ks = kk * 32 + l4 * 8;
    short8 a0 = *reinterpret_cast<const short8*>(&Ash[l15][ks]);
    short8 a1 = *reinterpret_cast<const short8*>(&Ash[16 + l15][ks]);
    short8 b  = *reinterpret_cast<const short8*>(Bp + ks);
    acc0 = __builtin_amdgcn_mfma_f32_16x16x32_bf16(a0, b, acc0, 0, 0, 0);
    acc1 = __builtin_amdgcn_mfma_f32_16x16x32_bf16(a1, b, acc1, 0, 0, 0);
  }
  // D layout: col = lane&15, row = (lane>>4)*4 + reg   [m89-verified]
  #pragma unroll
  for (int r = 0; r < 4; ++r) {
    Gsh[wave][l4 * 4 + r][l15]      = acc0[r];
    Gsh[wave][16 + l4 * 4 + r][l15] = acc1[r];
  }
  __syncthreads();

  // ---- fused gates + cell update + h write ----
  const int row = tid >> 3;            // 0..31
  const int c0 = (tid & 7) * 2;
  const int grow = rg * 32 + row;
  #pragma unroll
  for (int e = 0; e < 2; ++e) {
    int col = c0 + e;
    int hc = (cg << 4) + col;
    float gi = Gsh[0][row][col] + bi[hc];
    float gf = Gsh[1][row][col] + bf_[hc];
    float go = Gsh[2][row][col] + bo[hc];
    float gc = Gsh[3][row][col] + bc[hc];
    float it = 1.f / (1.f + __expf(-gi));
    float ft = 1.f / (1.f + __expf(-gf));
    float ot = 1.f / (1.f + __expf(-go));
    float ct = tanhf(gc);
    float cold = (t == 0) ? 0.f : C[grow * H_ + hc];
    float cnew = ft * cold + it * ct;
    C[grow * H_ + hc] = cnew;
    out[((size_t)grow * T_ + t) * H_ + hc] = ot * tanhf(cnew);
  }
}

extern "C" void kernel_launch(void* const* d_in, const int* in_sizes, int n_in,
                              void* d_out, int out_size, void* d_ws, size_t ws_size,
                              hipStream_t stream) {
  const float* x  = (const float*)d_in[0];
  const float* Wi = (const float*)d_in[1];
  const float* Ui = (const float*)d_in[2];
  const float* bi = (const float*)d_in[3];
  const float* Wf = (const float*)d_in[4];
  const float* Uf = (const float*)d_in[5];
  const float* bf = (const float*)d_in[6];
  const float* Wc = (const float*)d_in[7];
  const float* Uc = (const float*)d_in[8];
  const float* bc = (const float*)d_in[9];
  const float* Wo = (const float*)d_in[10];
  const float* Uo = (const float*)d_in[11];
  const float* bo = (const float*)d_in[12];
  float* out = (float*)d_out;

  unsigned short* BT = (unsigned short*)d_ws;                       // 3 MB
  float* C = (float*)((char*)d_ws + (size_t)NG_ * K_ * sizeof(unsigned short));

  prep_weights<<<(NG_ * K_ + 255) / 256, 256, 0, stream>>>(
      Wi, Wf, Wo, Wc, Ui, Uf, Uo, Uc, BT);
  for (int t = 0; t < T_; ++t) {
    lstm_step<<<256, 256, 0, stream>>>(x, BT, bi, bf, bo, bc, C, out, t);
  }
}